// Round 1
// 238.980 us; speedup vs baseline: 1.1897x; 1.1897x over previous
//
#include <hip/hip_runtime.h>
#include <hip/hip_bf16.h>

using bf16 = __hip_bfloat16;

typedef __attribute__((ext_vector_type(8))) __bf16 bf16x8;
typedef __attribute__((ext_vector_type(4))) float floatx4;

#define EPS 1e-6f

#define RAW_BARRIER()  asm volatile("s_barrier" ::: "memory")
#define WAIT_VM6()     asm volatile("s_waitcnt vmcnt(6)" ::: "memory")
#define WAIT_VM4()     asm volatile("s_waitcnt vmcnt(4)" ::: "memory")
#define WAIT_VM0()     asm volatile("s_waitcnt vmcnt(0)" ::: "memory")

__device__ __forceinline__ void load_lds16(const void* g, void* l) {
    __builtin_amdgcn_global_load_lds(
        (const __attribute__((address_space(1))) void*)g,
        (__attribute__((address_space(3))) void*)l, 16, 0, 0);
}

__device__ __forceinline__ void storeOut(float* p, float v) { *p = v; }
__device__ __forceinline__ void storeOut(bf16* p, float v) { *p = __float2bfloat16(v); }

// ---------------------------------------------------------------------------
// Canonical NT GEMM: D[m][n] = sum_k A[m][k] * B[n][k]
// BM x 128 block tile, BK=32, double-buffered LDS, manual vmcnt pipeline.
// Staging: 4-lane quads share one 64B line (r = idx>>2, quad = idx&3), so
// each global_load_lds instruction touches 16 cache lines instead of 64
// (the old r = idx&(BM-1) mapping was fully uncoalesced: 64 lines/instr,
// VMEM-request-rate bound at ~14% MfmaUtil).
// LDS layout is therefore [row][kquad] (64B rows); to keep ds_read_b128
// conflict-free the kquad slot is XOR-swizzled with (row>>1)&3, applied
// identically on the global source address and the LDS read address
// (global_load_lds dest stays linear in lane). addr16 = 4*row + kq^((row>>1)&3)
// walks all 8 bank-sets over 16 consecutive rows -> 2-way (free).
// BM=256: wave tile 128x64 (8x4 MFMA). BM=128: wave tile 64x64 (4x4).
// 1-D grid, XCD-aware decode (id&7 = XCD slot -> contiguous work chunk).
// QKV: n0>=1024 -> store transposed into vout (vv[c][j]).
// ---------------------------------------------------------------------------
template <int BM, int BIAS_MODE, int SCALE_EN, int RESID_EN, int EXP_MODE,
          int ROWDIV, int QKV, typename OutT>
__global__ __launch_bounds__(256, 2) void gemm_nt(
    const bf16* __restrict__ A, long long aStride, int lda,
    const bf16* __restrict__ B, long long bStride, int ldb,
    OutT* __restrict__ D, long long dStride, int ldd,
    bf16* __restrict__ vout, long long vStride,
    const float* __restrict__ bias,
    const float* __restrict__ resid, long long rStride, int ldr,
    float* __restrict__ rowsum, int rsStride,
    int K, float scale, int tpb, int gx)
{
    constexpr int MI = BM / 32;          // m-frags per wave (4 or 8)
    constexpr int NLA = BM / 64;         // A stage calls (2 or 4)
    constexpr int NL = NLA + 2;          // loads per stage

    __shared__ bf16 As[2][BM * 32];
    __shared__ bf16 Bs[2][128 * 32];

    const unsigned chunk = gridDim.x >> 3;
    const unsigned glob  = (blockIdx.x & 7) * chunk + (blockIdx.x >> 3);
    const unsigned z  = glob / (unsigned)tpb;
    const unsigned t  = glob % (unsigned)tpb;
    const int m0 = (int)(t / (unsigned)gx) * BM;
    const int n0 = (int)(t % (unsigned)gx) << 7;

    const int tid  = threadIdx.x;
    const int lane = tid & 63;
    const int wave = tid >> 6;
    const int wm   = wave >> 1;
    const int wn   = wave & 1;

    const bf16* Ab = A + (size_t)z * aStride + (size_t)m0 * lda;
    const bf16* Bb = B + (size_t)z * bStride + (size_t)n0 * ldb;

    floatx4 acc[MI][4];
#pragma unroll
    for (int i = 0; i < MI; ++i)
#pragma unroll
        for (int j = 0; j < 4; ++j) acc[i][j] = (floatx4){0.f, 0.f, 0.f, 0.f};

    const int laneRow = lane & 15;
    const int laneKq  = lane >> 4;
    // XOR-swizzled k-quad byte offset for LDS fragment reads. Fragment row
    // bases are multiples of 16, so (row>>1)&3 == (laneRow>>1)&3.
    const int kqs16 = (laneKq ^ ((laneRow >> 1) & 3)) << 4;

    auto stage = [&](int kt) {
        const int k0 = kt << 5;
        char* Ad = (char*)As[kt & 1];
        char* Bd = (char*)Bs[kt & 1];
#pragma unroll
        for (int t4 = 0; t4 < NLA; ++t4) {
            const int idx = tid + t4 * 256;
            const int r  = idx >> 2;
            const int qs = (idx & 3) ^ ((idx >> 3) & 3);
            load_lds16(Ab + (size_t)r * lda + k0 + qs * 8, Ad + idx * 16);
        }
#pragma unroll
        for (int t4 = 0; t4 < 2; ++t4) {
            const int idx = tid + t4 * 256;
            const int r  = idx >> 2;
            const int qs = (idx & 3) ^ ((idx >> 3) & 3);
            load_lds16(Bb + (size_t)r * ldb + k0 + qs * 8, Bd + idx * 16);
        }
    };

    const int kIters = K >> 5;
    stage(0);
    stage(1);
    for (int kt = 0; kt < kIters; ++kt) {
        if (kt + 1 < kIters) {
            if (NL == 6) { WAIT_VM6(); } else { WAIT_VM4(); }
        } else {
            WAIT_VM0();
        }
        RAW_BARRIER();

        const char* AsB = (const char*)As[kt & 1];
        const char* BsB = (const char*)Bs[kt & 1];
        bf16x8 af[MI], bfr[4];
#pragma unroll
        for (int im = 0; im < MI; ++im) {
            const int arow = wm * (BM / 2) + im * 16 + laneRow;
            af[im] = *(const bf16x8*)(AsB + arow * 64 + kqs16);
        }
#pragma unroll
        for (int in = 0; in < 4; ++in) {
            const int brow = wn * 64 + in * 16 + laneRow;
            bfr[in] = *(const bf16x8*)(BsB + brow * 64 + kqs16);
        }
#pragma unroll
        for (int im = 0; im < MI; ++im)
#pragma unroll
            for (int in = 0; in < 4; ++in)
                acc[im][in] = __builtin_amdgcn_mfma_f32_16x16x32_bf16(
                    af[im], bfr[in], acc[im][in], 0, 0, 0);

        RAW_BARRIER();
        if (kt + 2 < kIters) stage(kt + 2);
    }

    // Epilogue. C/D frag layout: col = lane&15, row = (lane>>4)*4 + reg
    const size_t dbase = (size_t)z * dStride;
#pragma unroll
    for (int im = 0; im < MI; ++im) {
        const int gmb = m0 + wm * (BM / 2) + im * 16 + (laneKq << 2);
        float ri[4];
        if (ROWDIV) {
#pragma unroll
            for (int r = 0; r < 4; ++r)
                ri[r] = 1.f / rowsum[(size_t)z * rsStride + gmb + r];
        }
        float rsum[4] = {0.f, 0.f, 0.f, 0.f};
#pragma unroll
        for (int in = 0; in < 4; ++in) {
            const int gn = n0 + wn * 64 + in * 16 + laneRow;
            float bn = 0.f;
            if (BIAS_MODE == 2) bn = bias[gn];
            if (QKV && n0 >= 1024) {
                union { bf16 h[4]; ushort4 u; } pk;
#pragma unroll
                for (int r = 0; r < 4; ++r)
                    pk.h[r] = __float2bfloat16(acc[im][in][r] + bn);
                *(ushort4*)(vout + (size_t)z * vStride +
                            (size_t)(gn - 1024) * 1024 + gmb) = pk.u;
            } else {
#pragma unroll
                for (int r = 0; r < 4; ++r) {
                    const int gm = gmb + r;
                    float v = acc[im][in][r];
                    if (SCALE_EN) v *= scale;
                    if (EXP_MODE) { v = __expf(v); rsum[r] += v; }
                    if (ROWDIV) v *= ri[r];
                    if (BIAS_MODE == 1) v += bias[gm];
                    if (BIAS_MODE == 2) v += bn;
                    if (RESID_EN)
                        v += resid[(size_t)z * rStride + (size_t)gm * ldr + gn];
                    storeOut(D + dbase + (size_t)gm * ldd + gn, v);
                }
            }
        }
        if (EXP_MODE) {
#pragma unroll
            for (int r = 0; r < 4; ++r) {
                float s = rsum[r];
                s += __shfl_xor(s, 1);
                s += __shfl_xor(s, 2);
                s += __shfl_xor(s, 4);
                s += __shfl_xor(s, 8);
                if (laneRow == 0)
                    atomicAdd(rowsum + (size_t)z * rsStride + gmb + r, s);
            }
        }
    }
}

// ---------------------------------------------------------------------------
// GroupNorm stats: one block per (b, g); 16 ch x 1024 = 16384 contiguous floats
// ---------------------------------------------------------------------------
__global__ __launch_bounds__(256) void gn_stats(const float* __restrict__ x,
                                                float* __restrict__ stats)
{
    const int bg = blockIdx.x;
    const float4* p = (const float4*)(x + (size_t)bg * 16384);
    float s = 0.f, ss = 0.f;
    for (int i = threadIdx.x; i < 4096; i += 256) {
        float4 v = p[i];
        s  += v.x + v.y + v.z + v.w;
        ss += v.x * v.x + v.y * v.y + v.z * v.z + v.w * v.w;
    }
#pragma unroll
    for (int off = 32; off; off >>= 1) {
        s  += __shfl_down(s, off);
        ss += __shfl_down(ss, off);
    }
    __shared__ float rs[4], rss[4];
    const int wv = threadIdx.x >> 6;
    if ((threadIdx.x & 63) == 0) { rs[wv] = s; rss[wv] = ss; }
    __syncthreads();
    if (threadIdx.x == 0) {
        float S  = rs[0] + rs[1] + rs[2] + rs[3];
        float SS = rss[0] + rss[1] + rss[2] + rss[3];
        float mean = S * (1.f / 16384.f);
        float var  = SS * (1.f / 16384.f) - mean * mean;
        stats[2 * bg]     = mean;
        stats[2 * bg + 1] = rsqrtf(var + EPS);
    }
}

// ---------------------------------------------------------------------------
// GN apply + transpose: x (B,512,1024) fp32 -> xnT (B,1024,512) bf16
// ---------------------------------------------------------------------------
__global__ __launch_bounds__(256) void gn_apply_t(const float* __restrict__ x,
                                                  const float* __restrict__ stats,
                                                  const float* __restrict__ gamma,
                                                  const float* __restrict__ beta,
                                                  bf16* __restrict__ xnT)
{
    __shared__ bf16 tile[32][36];
    const int b = blockIdx.z, c0 = blockIdx.y * 32, i0 = blockIdx.x * 32;
    {
        const int cc = threadIdx.x >> 3;
        const int i4 = (threadIdx.x & 7) << 2;
        const int c  = c0 + cc;
        const float mean = stats[2 * ((b << 5) + (c >> 4))];
        const float rstd = stats[2 * ((b << 5) + (c >> 4)) + 1];
        const float a  = gamma[c] * rstd;
        const float bb = beta[c] - mean * a;
        float4 v = *(const float4*)(x + (((size_t)(b * 512 + c)) << 10) + i0 + i4);
        tile[cc][i4 + 0] = __float2bfloat16(v.x * a + bb);
        tile[cc][i4 + 1] = __float2bfloat16(v.y * a + bb);
        tile[cc][i4 + 2] = __float2bfloat16(v.z * a + bb);
        tile[cc][i4 + 3] = __float2bfloat16(v.w * a + bb);
    }
    __syncthreads();
    {
        const int ii = threadIdx.x >> 3;
        const int c4 = (threadIdx.x & 7) << 2;
        union { bf16 h[4]; uint2 u; } pk;
        pk.h[0] = tile[c4 + 0][ii];
        pk.h[1] = tile[c4 + 1][ii];
        pk.h[2] = tile[c4 + 2][ii];
        pk.h[3] = tile[c4 + 3][ii];
        *((uint2*)(xnT + (((size_t)(b * 1024 + i0 + ii)) << 9) + c0 + c4)) = pk.u;
    }
}

// ---------------------------------------------------------------------------
// prep: weights fp32->bf16 (blocks 0..1023), qkv bias concat (block 1024),
// rowsum zero (block 1025).
// ---------------------------------------------------------------------------
__global__ __launch_bounds__(256) void prep(
    const float* __restrict__ wq, const float* __restrict__ wk,
    const float* __restrict__ wv, const float* __restrict__ wp,
    bf16* __restrict__ wqkvb, bf16* __restrict__ wpb,
    const float* __restrict__ bq, const float* __restrict__ bk,
    const float* __restrict__ bv, float* __restrict__ bqkv,
    float* __restrict__ rowsum)
{
    const int id = blockIdx.x;
    if (id < 1024) {
        const int w = id >> 8;
        const float* src = (w == 0) ? wq : (w == 1) ? wk : (w == 2) ? wv : wp;
        bf16* dst = (w < 3) ? (wqkvb + (size_t)w * 262144) : wpb;
        const int g = (id & 255) * 256 + threadIdx.x;
        float4 v = ((const float4*)src)[g];
        union { bf16 h[4]; uint2 u; } pk;
        pk.h[0] = __float2bfloat16(v.x);
        pk.h[1] = __float2bfloat16(v.y);
        pk.h[2] = __float2bfloat16(v.z);
        pk.h[3] = __float2bfloat16(v.w);
        ((uint2*)dst)[g] = pk.u;
    } else if (id == 1024) {
        for (int t = threadIdx.x; t < 1536; t += 256)
            bqkv[t] = (t < 512) ? bq[t] : (t < 1024) ? bk[t - 512] : bv[t - 1024];
    } else {
        float4 zero = {0.f, 0.f, 0.f, 0.f};
#pragma unroll
        for (int j = 0; j < 16; ++j)
            ((float4*)rowsum)[threadIdx.x + j * 256] = zero;
    }
}

// ---------------------------------------------------------------------------
extern "C" void kernel_launch(void* const* d_in, const int* in_sizes, int n_in,
                              void* d_out, int out_size, void* d_ws, size_t ws_size,
                              hipStream_t stream)
{
    const float* x     = (const float*)d_in[0];
    const float* gamma = (const float*)d_in[1];
    const float* beta  = (const float*)d_in[2];
    const float* wq    = (const float*)d_in[3];
    const float* bq    = (const float*)d_in[4];
    const float* wk    = (const float*)d_in[5];
    const float* bk    = (const float*)d_in[6];
    const float* wv    = (const float*)d_in[7];
    const float* bv    = (const float*)d_in[8];
    const float* wp    = (const float*)d_in[9];
    const float* bp    = (const float*)d_in[10];
    float* out = (float*)d_out;

    char* ws = (char*)d_ws;
    size_t off = 0;
    auto alloc = [&](size_t bytes) -> char* {
        char* p = ws + off;
        off += (bytes + 255) & ~(size_t)255;
        return p;
    };

    const long long S  = 1024, C = 512;
    const long long BS = S * C;
    const long long ES = S * S;

    float* stats  = (float*)alloc(512 * 2 * sizeof(float));
    float* bqkv   = (float*)alloc(1536 * sizeof(float));
    float* rowsum = (float*)alloc((size_t)16 * S * sizeof(float));
    bf16* wqkvb = (bf16*)alloc((size_t)3 * C * C * 2);  // [wq; wk; wv]
    bf16* wpb   = (bf16*)alloc((size_t)C * C * 2);
    bf16* xnT   = (bf16*)alloc((size_t)16 * BS * 2);
    bf16* qkT   = (bf16*)alloc((size_t)16 * ES * 2);    // (B,1024,1024): [qT|kT]
    bf16* vv    = (bf16*)alloc((size_t)16 * BS * 2);    // (B,512,1024)
    bf16* O2    = (bf16*)alloc((size_t)16 * BS * 2);

    int CB = 16;
    while (CB > 1 && off + (size_t)CB * ES * 2 + 1024 > ws_size) CB >>= 1;
    bf16* P = (bf16*)alloc((size_t)CB * ES * 2);

    prep<<<1026, 256, 0, stream>>>(wq, wk, wv, wp, wqkvb, wpb, bq, bk, bv,
                                   bqkv, rowsum);

    gn_stats<<<512, 256, 0, stream>>>(x, stats);
    gn_apply_t<<<dim3(32, 16, 16), 256, 0, stream>>>(x, stats, gamma, beta, xnT);

    // QKV proj: M=1024 (i), N=1536 ([q|k|v]), K=512, Z=16. BM=256.
    gemm_nt<256, 2, 0, 0, 0, 0, 1, bf16><<<768, 256, 0, stream>>>(
        xnT, BS, 512, wqkvb, 0, 512, qkT, ES, 1024, vv, BS,
        bqkv, nullptr, 0, 0, nullptr, 0, 512, 1.f, /*tpb*/48, /*gx*/12);

    const float scale = 0.044194173824159216f; // 512^-0.5
    for (int b0 = 0; b0 < 16; b0 += CB) {
        // P[i][j] = exp(scale * q_i.k_j); rowsum[i] += (atomics). BM=256.
        gemm_nt<256, 0, 1, 0, 1, 0, 0, bf16><<<CB * 32, 256, 0, stream>>>(
            qkT + (size_t)b0 * ES, ES, 1024,
            qkT + (size_t)b0 * ES + 512, ES, 1024,
            P, ES, 1024, nullptr, 0,
            nullptr, nullptr, 0, 0, rowsum + (size_t)b0 * S, (int)S,
            512, scale, /*tpb*/32, /*gx*/8);
        // O2[i][c] = (sum_j P[i][j] vv[c][j]) / rowsum[i]. BM=128 (2 blk/CU).
        gemm_nt<128, 0, 0, 0, 0, 1, 0, bf16><<<CB * 32, 256, 0, stream>>>(
            P, ES, 1024,
            vv + (size_t)b0 * BS, BS, 1024,
            O2 + (size_t)b0 * BS, BS, 512, nullptr, 0,
            nullptr, nullptr, 0, 0, rowsum + (size_t)b0 * S, (int)S,
            1024, 1.f, /*tpb*/32, /*gx*/4);
    }

    // out[o][i] = sum_c wp[o][c] O2[i][c] + bp[o] + x[o][i]. BM=128.
    gemm_nt<128, 1, 0, 1, 0, 0, 0, float><<<512, 256, 0, stream>>>(
        wpb, 0, 512, O2, BS, 512, out, BS, 1024, nullptr, 0,
        bp, x, BS, 1024, nullptr, 0, 512, 1.f, /*tpb*/32, /*gx*/8);
}

// Round 2
// 229.584 us; speedup vs baseline: 1.2384x; 1.0409x over previous
//
#include <hip/hip_runtime.h>
#include <hip/hip_bf16.h>

using bf16 = __hip_bfloat16;

typedef __attribute__((ext_vector_type(8))) __bf16 bf16x8;
typedef __attribute__((ext_vector_type(4))) float floatx4;

#define EPS 1e-6f

#define RAW_BARRIER()  asm volatile("s_barrier" ::: "memory")
#define WAIT_VM8()     asm volatile("s_waitcnt vmcnt(8)" ::: "memory")
#define WAIT_VM6()     asm volatile("s_waitcnt vmcnt(6)" ::: "memory")
#define WAIT_VM4()     asm volatile("s_waitcnt vmcnt(4)" ::: "memory")
#define WAIT_VM3()     asm volatile("s_waitcnt vmcnt(3)" ::: "memory")
#define WAIT_VM0()     asm volatile("s_waitcnt vmcnt(0)" ::: "memory")
#define PRIO1()        __builtin_amdgcn_s_setprio(1)
#define PRIO0()        __builtin_amdgcn_s_setprio(0)

__device__ __forceinline__ void load_lds16(const void* g, void* l) {
    __builtin_amdgcn_global_load_lds(
        (const __attribute__((address_space(1))) void*)g,
        (__attribute__((address_space(3))) void*)l, 16, 0, 0);
}

__device__ __forceinline__ void storeOut(float* p, float v) { *p = v; }
__device__ __forceinline__ void storeOut(bf16* p, float v) { *p = __float2bfloat16(v); }

#define MFMA16(a, b, c) __builtin_amdgcn_mfma_f32_16x16x32_bf16(a, b, c, 0, 0, 0)

// ---------------------------------------------------------------------------
// 8-phase NT GEMM (m201-style): D[m][n] = sum_k A[m][k] * B[n][k]
// BM=256, BN = NI*64 (256 or 128), BK=64, 512 threads = 8 waves (2M x 4N).
// Wave tile: 128 x NI*16. acc = 8 x NI floatx4.
// LDS (dynamic): A 4x16KB halves + B 4x(BN*64)B halves, double-buffered by
// K-tile, split by k-half. Per K-tile: 4 phases (NI=4) / 2 phases (NI=2),
// each phase = {ds_read frag subtile; stage one half-tile of a future tile;
// barrier; setprio(1); 16 MFMA; setprio(0); barrier}. Counted vmcnt twice
// per K-tile (NI=4: vmcnt(8); NI=2: vmcnt(6)); never 0 except last tile.
// Stage mapping (NI=4): P1->(t+1,A,k1), P2->(t+1,B,k1), P3->(t+2,A,k0),
// P4->(t+2,B,k0). Prologue stages (0,*,*) and (1,*,k0). Ledgered: boundary
// vmcnt(8) covers (t,k0) halves, mid vmcnt(8) covers (t,k1); prefetch is
// ~6 phases deep (> HBM latency). Buffer write-after-read safety comes from
// phase barriers (k0 regions of buf t&1 are re-staged only after P2's reads
// completed; other-buffer k1 halves only after tile t-1 finished).
// Staging layout per half (row r, kquad q): slot idx = r*4 + (q^((r>>1)&3)),
// 4-lane quads share one 64B line (coalesced); reads use the same XOR.
// 1-D grid, XCD-aware decode. QKV: n0>=1024 -> store transposed into vout.
// ---------------------------------------------------------------------------
template <int NI, int BIAS_MODE, int SCALE_EN, int RESID_EN, int EXP_MODE,
          int ROWDIV, int QKV, typename OutT>
__global__ __launch_bounds__(512, 2) void gemm8(
    const bf16* __restrict__ A, long long aStride, int lda,
    const bf16* __restrict__ B, long long bStride, int ldb,
    OutT* __restrict__ D, long long dStride, int ldd,
    bf16* __restrict__ vout, long long vStride,
    const float* __restrict__ bias,
    const float* __restrict__ resid, long long rStride, int ldr,
    float* __restrict__ rowsum, int rsStride,
    int K, float scale, int tpb, int gx)
{
    constexpr int BN  = NI * 64;
    constexpr int ABH = 16384;      // A bytes per (buf, khalf): 256 rows x 32k x 2B
    constexpr int BBH = BN * 64;    // B bytes per (buf, khalf)
    extern __shared__ char smem[];

    const unsigned chunk = gridDim.x >> 3;
    const unsigned glob  = (blockIdx.x & 7) * chunk + (blockIdx.x >> 3);
    const unsigned z  = glob / (unsigned)tpb;
    const unsigned t  = glob % (unsigned)tpb;
    const int m0 = (int)(t / (unsigned)gx) << 8;
    const int n0 = (int)(t % (unsigned)gx) * BN;

    const int tid  = threadIdx.x;
    const int lane = tid & 63;
    const int wave = tid >> 6;
    const int wm   = wave >> 2;          // 0..1
    const int wn   = wave & 3;           // 0..3

    const bf16* Ab = A + (size_t)z * aStride + (size_t)m0 * lda;
    const bf16* Bb = B + (size_t)z * bStride + (size_t)n0 * ldb;

    floatx4 acc[8][NI];
#pragma unroll
    for (int i = 0; i < 8; ++i)
#pragma unroll
        for (int j = 0; j < NI; ++j) acc[i][j] = (floatx4){0.f, 0.f, 0.f, 0.f};

    const int laneRow = lane & 15;
    const int laneKq  = lane >> 4;
    const int kqs16   = (laneKq ^ ((laneRow >> 1) & 3)) << 4;
    const int arow0   = wm * 128 + laneRow;
    const int brow0   = wn * (NI * 16) + laneRow;

    auto stageA = [&](int kt, int h) {
        char* dst = smem + ((kt & 1) * 2 + h) * ABH;
        const int kb = (kt << 6) + (h << 5);
#pragma unroll
        for (int u = 0; u < 2; ++u) {
            const int idx = tid + u * 512;
            const int r  = idx >> 2;
            const int qs = (idx & 3) ^ ((idx >> 3) & 3);
            load_lds16(Ab + (size_t)r * lda + kb + qs * 8, dst + idx * 16);
        }
    };
    auto stageB = [&](int kt, int h) {
        char* dst = smem + 4 * ABH + ((kt & 1) * 2 + h) * BBH;
        const int kb = (kt << 6) + (h << 5);
        if constexpr (NI == 4) {
#pragma unroll
            for (int u = 0; u < 2; ++u) {
                const int idx = tid + u * 512;
                const int r  = idx >> 2;
                const int qs = (idx & 3) ^ ((idx >> 3) & 3);
                load_lds16(Bb + (size_t)r * ldb + kb + qs * 8, dst + idx * 16);
            }
        } else {
            const int idx = tid;
            const int r  = idx >> 2;
            const int qs = (idx & 3) ^ ((idx >> 3) & 3);
            load_lds16(Bb + (size_t)r * ldb + kb + qs * 8, dst + idx * 16);
        }
    };

    const int nt = K >> 6;
    // Prologue: tile0 fully, tile1 k0 halves.
    stageA(0, 0); stageB(0, 0); stageA(0, 1); stageB(0, 1);
    stageA(1, 0); stageB(1, 0);

    for (int kt = 0; kt < nt; ++kt) {
        const char* Ablk = smem + (kt & 1) * 2 * ABH;
        const char* Bblk = smem + 4 * ABH + (kt & 1) * 2 * BBH;
        const bool lastT = (kt == nt - 1);

        // boundary wait: need (kt, k0) halves landed
        if (lastT) { if constexpr (NI == 4) WAIT_VM4(); else WAIT_VM3(); }
        else       { if constexpr (NI == 4) WAIT_VM8(); else WAIT_VM6(); }
        RAW_BARRIER();

        if constexpr (NI == 4) {
            bf16x8 af[4], bfr[4];
            // ---- P1: (m0-3, k0) ----
#pragma unroll
            for (int im = 0; im < 4; ++im)
                af[im] = *(const bf16x8*)(Ablk + (arow0 + im * 16) * 64 + kqs16);
#pragma unroll
            for (int in = 0; in < 4; ++in)
                bfr[in] = *(const bf16x8*)(Bblk + (brow0 + in * 16) * 64 + kqs16);
            if (kt + 1 < nt) stageA(kt + 1, 1);
            RAW_BARRIER();
            PRIO1();
#pragma unroll
            for (int im = 0; im < 4; ++im)
#pragma unroll
                for (int in = 0; in < 4; ++in)
                    acc[im][in] = MFMA16(af[im], bfr[in], acc[im][in]);
            PRIO0();
            RAW_BARRIER();
            // ---- P2: (m4-7, k0) ----
#pragma unroll
            for (int im = 0; im < 4; ++im)
                af[im] = *(const bf16x8*)(Ablk + (arow0 + (im + 4) * 16) * 64 + kqs16);
            if (kt + 1 < nt) stageB(kt + 1, 1);
            RAW_BARRIER();
            PRIO1();
#pragma unroll
            for (int im = 0; im < 4; ++im)
#pragma unroll
                for (int in = 0; in < 4; ++in)
                    acc[im + 4][in] = MFMA16(af[im], bfr[in], acc[im + 4][in]);
            PRIO0();
            // mid wait: need (kt, k1) halves landed
            if (lastT) WAIT_VM0(); else WAIT_VM8();
            RAW_BARRIER();
            // ---- P3: (m0-3, k1) ----
#pragma unroll
            for (int im = 0; im < 4; ++im)
                af[im] = *(const bf16x8*)(Ablk + ABH + (arow0 + im * 16) * 64 + kqs16);
#pragma unroll
            for (int in = 0; in < 4; ++in)
                bfr[in] = *(const bf16x8*)(Bblk + BBH + (brow0 + in * 16) * 64 + kqs16);
            if (kt + 2 < nt) stageA(kt + 2, 0);
            RAW_BARRIER();
            PRIO1();
#pragma unroll
            for (int im = 0; im < 4; ++im)
#pragma unroll
                for (int in = 0; in < 4; ++in)
                    acc[im][in] = MFMA16(af[im], bfr[in], acc[im][in]);
            PRIO0();
            RAW_BARRIER();
            // ---- P4: (m4-7, k1) ----
#pragma unroll
            for (int im = 0; im < 4; ++im)
                af[im] = *(const bf16x8*)(Ablk + ABH + (arow0 + (im + 4) * 16) * 64 + kqs16);
            if (kt + 2 < nt) stageB(kt + 2, 0);
            RAW_BARRIER();
            PRIO1();
#pragma unroll
            for (int im = 0; im < 4; ++im)
#pragma unroll
                for (int in = 0; in < 4; ++in)
                    acc[im + 4][in] = MFMA16(af[im], bfr[in], acc[im + 4][in]);
            PRIO0();
            // trailing barrier provided by next iteration's boundary barrier
        } else {
            bf16x8 af[8], bfr[2];
            // ---- P1: all m, k0 ----
#pragma unroll
            for (int im = 0; im < 8; ++im)
                af[im] = *(const bf16x8*)(Ablk + (arow0 + im * 16) * 64 + kqs16);
#pragma unroll
            for (int in = 0; in < 2; ++in)
                bfr[in] = *(const bf16x8*)(Bblk + (brow0 + in * 16) * 64 + kqs16);
            if (kt + 1 < nt) { stageA(kt + 1, 1); stageB(kt + 1, 1); }
            RAW_BARRIER();
            PRIO1();
#pragma unroll
            for (int im = 0; im < 8; ++im)
#pragma unroll
                for (int in = 0; in < 2; ++in)
                    acc[im][in] = MFMA16(af[im], bfr[in], acc[im][in]);
            PRIO0();
            if (lastT) WAIT_VM0(); else WAIT_VM6();
            RAW_BARRIER();
            // ---- P2: all m, k1 ----
#pragma unroll
            for (int im = 0; im < 8; ++im)
                af[im] = *(const bf16x8*)(Ablk + ABH + (arow0 + im * 16) * 64 + kqs16);
#pragma unroll
            for (int in = 0; in < 2; ++in)
                bfr[in] = *(const bf16x8*)(Bblk + BBH + (brow0 + in * 16) * 64 + kqs16);
            if (kt + 2 < nt) { stageA(kt + 2, 0); stageB(kt + 2, 0); }
            RAW_BARRIER();
            PRIO1();
#pragma unroll
            for (int im = 0; im < 8; ++im)
#pragma unroll
                for (int in = 0; in < 2; ++in)
                    acc[im][in] = MFMA16(af[im], bfr[in], acc[im][in]);
            PRIO0();
        }
    }

    // Epilogue. C/D frag layout: col = lane&15, row = (lane>>4)*4 + reg
    const size_t dbase = (size_t)z * dStride;
#pragma unroll
    for (int im = 0; im < 8; ++im) {
        const int gmb = m0 + wm * 128 + im * 16 + (laneKq << 2);
        float ri[4];
        if (ROWDIV) {
#pragma unroll
            for (int r = 0; r < 4; ++r)
                ri[r] = 1.f / rowsum[(size_t)z * rsStride + gmb + r];
        }
        float rsum[4] = {0.f, 0.f, 0.f, 0.f};
#pragma unroll
        for (int in = 0; in < NI; ++in) {
            const int gn = n0 + wn * (NI * 16) + in * 16 + laneRow;
            float bn = 0.f;
            if (BIAS_MODE == 2) bn = bias[gn];
            if (QKV && n0 >= 1024) {
                union { bf16 h[4]; ushort4 u; } pk;
#pragma unroll
                for (int r = 0; r < 4; ++r)
                    pk.h[r] = __float2bfloat16(acc[im][in][r] + bn);
                *(ushort4*)(vout + (size_t)z * vStride +
                            (size_t)(gn - 1024) * 1024 + gmb) = pk.u;
            } else {
#pragma unroll
                for (int r = 0; r < 4; ++r) {
                    const int gm = gmb + r;
                    float v = acc[im][in][r];
                    if (SCALE_EN) v *= scale;
                    if (EXP_MODE) { v = __expf(v); rsum[r] += v; }
                    if (ROWDIV) v *= ri[r];
                    if (BIAS_MODE == 1) v += bias[gm];
                    if (BIAS_MODE == 2) v += bn;
                    if (RESID_EN)
                        v += resid[(size_t)z * rStride + (size_t)gm * ldr + gn];
                    storeOut(D + dbase + (size_t)gm * ldd + gn, v);
                }
            }
        }
        if (EXP_MODE) {
#pragma unroll
            for (int r = 0; r < 4; ++r) {
                float s = rsum[r];
                s += __shfl_xor(s, 1);
                s += __shfl_xor(s, 2);
                s += __shfl_xor(s, 4);
                s += __shfl_xor(s, 8);
                if (laneRow == 0)
                    atomicAdd(rowsum + (size_t)z * rsStride + gmb + r, s);
            }
        }
    }
}

// ---------------------------------------------------------------------------
// GroupNorm stats: one block per (b, g); 16 ch x 1024 = 16384 contiguous floats
// ---------------------------------------------------------------------------
__global__ __launch_bounds__(256) void gn_stats(const float* __restrict__ x,
                                                float* __restrict__ stats)
{
    const int bg = blockIdx.x;
    const float4* p = (const float4*)(x + (size_t)bg * 16384);
    float s = 0.f, ss = 0.f;
    for (int i = threadIdx.x; i < 4096; i += 256) {
        float4 v = p[i];
        s  += v.x + v.y + v.z + v.w;
        ss += v.x * v.x + v.y * v.y + v.z * v.z + v.w * v.w;
    }
#pragma unroll
    for (int off = 32; off; off >>= 1) {
        s  += __shfl_down(s, off);
        ss += __shfl_down(ss, off);
    }
    __shared__ float rs[4], rss[4];
    const int wv = threadIdx.x >> 6;
    if ((threadIdx.x & 63) == 0) { rs[wv] = s; rss[wv] = ss; }
    __syncthreads();
    if (threadIdx.x == 0) {
        float S  = rs[0] + rs[1] + rs[2] + rs[3];
        float SS = rss[0] + rss[1] + rss[2] + rss[3];
        float mean = S * (1.f / 16384.f);
        float var  = SS * (1.f / 16384.f) - mean * mean;
        stats[2 * bg]     = mean;
        stats[2 * bg + 1] = rsqrtf(var + EPS);
    }
}

// ---------------------------------------------------------------------------
// GN apply + transpose: x (B,512,1024) fp32 -> xnT (B,1024,512) bf16
// ---------------------------------------------------------------------------
__global__ __launch_bounds__(256) void gn_apply_t(const float* __restrict__ x,
                                                  const float* __restrict__ stats,
                                                  const float* __restrict__ gamma,
                                                  const float* __restrict__ beta,
                                                  bf16* __restrict__ xnT)
{
    __shared__ bf16 tile[32][36];
    const int b = blockIdx.z, c0 = blockIdx.y * 32, i0 = blockIdx.x * 32;
    {
        const int cc = threadIdx.x >> 3;
        const int i4 = (threadIdx.x & 7) << 2;
        const int c  = c0 + cc;
        const float mean = stats[2 * ((b << 5) + (c >> 4))];
        const float rstd = stats[2 * ((b << 5) + (c >> 4)) + 1];
        const float a  = gamma[c] * rstd;
        const float bb = beta[c] - mean * a;
        float4 v = *(const float4*)(x + (((size_t)(b * 512 + c)) << 10) + i0 + i4);
        tile[cc][i4 + 0] = __float2bfloat16(v.x * a + bb);
        tile[cc][i4 + 1] = __float2bfloat16(v.y * a + bb);
        tile[cc][i4 + 2] = __float2bfloat16(v.z * a + bb);
        tile[cc][i4 + 3] = __float2bfloat16(v.w * a + bb);
    }
    __syncthreads();
    {
        const int ii = threadIdx.x >> 3;
        const int c4 = (threadIdx.x & 7) << 2;
        union { bf16 h[4]; uint2 u; } pk;
        pk.h[0] = tile[c4 + 0][ii];
        pk.h[1] = tile[c4 + 1][ii];
        pk.h[2] = tile[c4 + 2][ii];
        pk.h[3] = tile[c4 + 3][ii];
        *((uint2*)(xnT + (((size_t)(b * 1024 + i0 + ii)) << 9) + c0 + c4)) = pk.u;
    }
}

// ---------------------------------------------------------------------------
// prep: weights fp32->bf16 (blocks 0..1023), qkv bias concat (block 1024),
// rowsum zero (block 1025).
// ---------------------------------------------------------------------------
__global__ __launch_bounds__(256) void prep(
    const float* __restrict__ wq, const float* __restrict__ wk,
    const float* __restrict__ wv, const float* __restrict__ wp,
    bf16* __restrict__ wqkvb, bf16* __restrict__ wpb,
    const float* __restrict__ bq, const float* __restrict__ bk,
    const float* __restrict__ bv, float* __restrict__ bqkv,
    float* __restrict__ rowsum)
{
    const int id = blockIdx.x;
    if (id < 1024) {
        const int w = id >> 8;
        const float* src = (w == 0) ? wq : (w == 1) ? wk : (w == 2) ? wv : wp;
        bf16* dst = (w < 3) ? (wqkvb + (size_t)w * 262144) : wpb;
        const int g = (id & 255) * 256 + threadIdx.x;
        float4 v = ((const float4*)src)[g];
        union { bf16 h[4]; uint2 u; } pk;
        pk.h[0] = __float2bfloat16(v.x);
        pk.h[1] = __float2bfloat16(v.y);
        pk.h[2] = __float2bfloat16(v.z);
        pk.h[3] = __float2bfloat16(v.w);
        ((uint2*)dst)[g] = pk.u;
    } else if (id == 1024) {
        for (int t = threadIdx.x; t < 1536; t += 256)
            bqkv[t] = (t < 512) ? bq[t] : (t < 1024) ? bk[t - 512] : bv[t - 1024];
    } else {
        float4 zero = {0.f, 0.f, 0.f, 0.f};
#pragma unroll
        for (int j = 0; j < 16; ++j)
            ((float4*)rowsum)[threadIdx.x + j * 256] = zero;
    }
}

// ---------------------------------------------------------------------------
extern "C" void kernel_launch(void* const* d_in, const int* in_sizes, int n_in,
                              void* d_out, int out_size, void* d_ws, size_t ws_size,
                              hipStream_t stream)
{
    const float* x     = (const float*)d_in[0];
    const float* gamma = (const float*)d_in[1];
    const float* beta  = (const float*)d_in[2];
    const float* wq    = (const float*)d_in[3];
    const float* bq    = (const float*)d_in[4];
    const float* wk    = (const float*)d_in[5];
    const float* bk    = (const float*)d_in[6];
    const float* wv    = (const float*)d_in[7];
    const float* bv    = (const float*)d_in[8];
    const float* wp    = (const float*)d_in[9];
    const float* bp    = (const float*)d_in[10];
    float* out = (float*)d_out;

    char* ws = (char*)d_ws;
    size_t off = 0;
    auto alloc = [&](size_t bytes) -> char* {
        char* p = ws + off;
        off += (bytes + 255) & ~(size_t)255;
        return p;
    };

    const long long S  = 1024, C = 512;
    const long long BS = S * C;
    const long long ES = S * S;

    float* stats  = (float*)alloc(512 * 2 * sizeof(float));
    float* bqkv   = (float*)alloc(1536 * sizeof(float));
    float* rowsum = (float*)alloc((size_t)16 * S * sizeof(float));
    bf16* wqkvb = (bf16*)alloc((size_t)3 * C * C * 2);  // [wq; wk; wv]
    bf16* wpb   = (bf16*)alloc((size_t)C * C * 2);
    bf16* xnT   = (bf16*)alloc((size_t)16 * BS * 2);
    bf16* qkT   = (bf16*)alloc((size_t)16 * ES * 2);    // (B,1024,1024): [qT|kT]
    bf16* vv    = (bf16*)alloc((size_t)16 * BS * 2);    // (B,512,1024)
    bf16* O2    = (bf16*)alloc((size_t)16 * BS * 2);

    int CB = 16;
    while (CB > 1 && off + (size_t)CB * ES * 2 + 1024 > ws_size) CB >>= 1;
    bf16* P = (bf16*)alloc((size_t)CB * ES * 2);

    // Allow 128KB / 96KB dynamic LDS for the 8-phase GEMMs (graph-safe:
    // hipFuncSetAttribute is an immediate module-state call, not a stream op).
    hipFuncSetAttribute((const void*)gemm8<4, 2, 0, 0, 0, 0, 1, bf16>,
                        hipFuncAttributeMaxDynamicSharedMemorySize, 131072);
    hipFuncSetAttribute((const void*)gemm8<4, 0, 1, 0, 1, 0, 0, bf16>,
                        hipFuncAttributeMaxDynamicSharedMemorySize, 131072);
    hipFuncSetAttribute((const void*)gemm8<2, 0, 0, 0, 0, 1, 0, bf16>,
                        hipFuncAttributeMaxDynamicSharedMemorySize, 98304);
    hipFuncSetAttribute((const void*)gemm8<2, 1, 0, 1, 0, 0, 0, float>,
                        hipFuncAttributeMaxDynamicSharedMemorySize, 98304);

    prep<<<1026, 256, 0, stream>>>(wq, wk, wv, wp, wqkvb, wpb, bq, bk, bv,
                                   bqkv, rowsum);

    gn_stats<<<512, 256, 0, stream>>>(x, stats);
    gn_apply_t<<<dim3(32, 16, 16), 256, 0, stream>>>(x, stats, gamma, beta, xnT);

    // QKV proj: M=1024 (i), N=1536 ([q|k|v]), K=512, Z=16. BN=256 -> 384 blocks.
    gemm8<4, 2, 0, 0, 0, 0, 1, bf16><<<384, 512, 131072, stream>>>(
        xnT, BS, 512, wqkvb, 0, 512, qkT, ES, 1024, vv, BS,
        bqkv, nullptr, 0, 0, nullptr, 0, 512, 1.f, /*tpb*/24, /*gx*/6);

    const float scale = 0.044194173824159216f; // 512^-0.5
    for (int b0 = 0; b0 < 16; b0 += CB) {
        // P[i][j] = exp(scale * q_i.k_j); rowsum[i] += (atomics). BN=256.
        gemm8<4, 0, 1, 0, 1, 0, 0, bf16><<<CB * 16, 512, 131072, stream>>>(
            qkT + (size_t)b0 * ES, ES, 1024,
            qkT + (size_t)b0 * ES + 512, ES, 1024,
            P, ES, 1024, nullptr, 0,
            nullptr, nullptr, 0, 0, rowsum + (size_t)b0 * S, (int)S,
            512, scale, /*tpb*/16, /*gx*/4);
        // O2[i][c] = (sum_j P[i][j] vv[c][j]) / rowsum[i]. BN=128.
        gemm8<2, 0, 0, 0, 0, 1, 0, bf16><<<CB * 16, 512, 98304, stream>>>(
            P, ES, 1024,
            vv + (size_t)b0 * BS, BS, 1024,
            O2 + (size_t)b0 * BS, BS, 512, nullptr, 0,
            nullptr, nullptr, 0, 0, rowsum + (size_t)b0 * S, (int)S,
            1024, 1.f, /*tpb*/16, /*gx*/4);
    }

    // out[o][i] = sum_c wp[o][c] O2[i][c] + bp[o] + x[o][i]. BN=128, M=512.
    gemm8<2, 1, 0, 1, 0, 0, 0, float><<<256, 512, 98304, stream>>>(
        wpb, 0, 512, O2, BS, 512, out, BS, 1024, nullptr, 0,
        bp, x, BS, 1024, nullptr, 0, 512, 1.f, /*tpb*/16, /*gx*/8);
}

// Round 3
// 224.996 us; speedup vs baseline: 1.2636x; 1.0204x over previous
//
#include <hip/hip_runtime.h>
#include <hip/hip_bf16.h>

using bf16 = __hip_bfloat16;

typedef __attribute__((ext_vector_type(8))) __bf16 bf16x8;
typedef __attribute__((ext_vector_type(4))) float floatx4;

#define EPS 1e-6f

#define RAW_BARRIER()  asm volatile("s_barrier" ::: "memory")
#define WAIT_VM8()     asm volatile("s_waitcnt vmcnt(8)" ::: "memory")
#define WAIT_VM4()     asm volatile("s_waitcnt vmcnt(4)" ::: "memory")
#define WAIT_VM0()     asm volatile("s_waitcnt vmcnt(0)" ::: "memory")
#define PRIO1()        __builtin_amdgcn_s_setprio(1)
#define PRIO0()        __builtin_amdgcn_s_setprio(0)

__device__ __forceinline__ void load_lds16(const void* g, void* l) {
    __builtin_amdgcn_global_load_lds(
        (const __attribute__((address_space(1))) void*)g,
        (__attribute__((address_space(3))) void*)l, 16, 0, 0);
}

__device__ __forceinline__ void storeOut(float* p, float v) { *p = v; }
__device__ __forceinline__ void storeOut(bf16* p, float v) { *p = __float2bfloat16(v); }

#define MFMA16(a, b, c) __builtin_amdgcn_mfma_f32_16x16x32_bf16(a, b, c, 0, 0, 0)

// ---------------------------------------------------------------------------
// 2-blocks/CU pipelined NT GEMM: D[m][n] = sum_k A[m][k] * B[n][k]
// BM=BN=128, BK=64 (k-half split), 256 threads = 4 waves (2M x 2N).
// Wave tile 64x64: acc[4][4] floatx4. LDS 64KB dynamic -> 2 blocks/CU, so
// two INDEPENDENT barrier groups per CU: when one block's waves stall at a
// phase barrier, the other block's waves issue MFMA (m97 mechanism) — on top
// of the counted-vmcnt pipeline (T3/T4) and setprio (T5).
// Per K-tile, 2 phases: {waitVM; BAR; ds_read 8 frags (k-half); stage 4
// global_load_lds; BAR; prio1; 16 MFMA; prio0}. Stage mapping: phase1(kt) ->
// (kt+1, k1) [other buf], phase2(kt) -> (kt+2, k0) [same buf]. Ledger:
// prologue 12 loads; steady-state waits both vmcnt(8) (12 in flight, ~1.5
// K-tiles deep); last tile vmcnt(4)/vmcnt(0). Buffer WAR safety: staged
// regions' previous readers completed their MFMA before the preceding
// barrier (verified per region).
// Staging layout per 8KB half (row r, kquad q): slot = r*4 + (q^((r>>1)&3));
// 4-lane quads share one 64B line (coalesced); read addr = row*64 +
// ((laneKq^((laneRow>>1)&3))<<4) -> 2-way bank aliasing (free, 0 conflicts
// measured). global_load_lds dest stays linear in lane (wave-uniform base).
// 1-D grid, XCD-aware decode. QKV: n0>=1024 -> store transposed into vout.
// ---------------------------------------------------------------------------
template <int BIAS_MODE, int SCALE_EN, int RESID_EN, int EXP_MODE,
          int ROWDIV, int QKV, typename OutT>
__global__ __launch_bounds__(256, 2) void gemm2b(
    const bf16* __restrict__ A, long long aStride, int lda,
    const bf16* __restrict__ B, long long bStride, int ldb,
    OutT* __restrict__ D, long long dStride, int ldd,
    bf16* __restrict__ vout, long long vStride,
    const float* __restrict__ bias,
    const float* __restrict__ resid, long long rStride, int ldr,
    float* __restrict__ rowsum, int rsStride,
    int K, float scale, int tpb, int gx)
{
    constexpr int HB = 8192;   // bytes per (buf, khalf) per operand: 128x32x2B
    extern __shared__ char smem[];

    const unsigned chunk = gridDim.x >> 3;
    const unsigned glob  = (blockIdx.x & 7) * chunk + (blockIdx.x >> 3);
    const unsigned z  = glob / (unsigned)tpb;
    const unsigned t  = glob % (unsigned)tpb;
    const int m0 = (int)(t / (unsigned)gx) << 7;
    const int n0 = (int)(t % (unsigned)gx) << 7;

    const int tid  = threadIdx.x;
    const int lane = tid & 63;
    const int wave = tid >> 6;
    const int wm   = wave >> 1;          // 0..1
    const int wn   = wave & 1;           // 0..1

    const bf16* Ab = A + (size_t)z * aStride + (size_t)m0 * lda;
    const bf16* Bb = B + (size_t)z * bStride + (size_t)n0 * ldb;

    floatx4 acc[4][4];
#pragma unroll
    for (int i = 0; i < 4; ++i)
#pragma unroll
        for (int j = 0; j < 4; ++j) acc[i][j] = (floatx4){0.f, 0.f, 0.f, 0.f};

    const int laneRow = lane & 15;
    const int laneKq  = lane >> 4;
    const int kqs16   = (laneKq ^ ((laneRow >> 1) & 3)) << 4;
    const int arow0   = wm * 64 + laneRow;
    const int brow0   = wn * 64 + laneRow;

    // stage one (buf, khalf) pair for A and B: 2+2 load_lds16 per thread
    auto stage = [&](int kt, int h) {
        char* Adst = smem + ((kt & 1) * 2 + h) * HB;
        char* Bdst = smem + 4 * HB + ((kt & 1) * 2 + h) * HB;
        const int kb = (kt << 6) + (h << 5);
#pragma unroll
        for (int u = 0; u < 2; ++u) {
            const int idx = tid + u * 256;
            const int r  = idx >> 2;
            const int qs = (idx & 3) ^ ((idx >> 3) & 3);
            load_lds16(Ab + (size_t)r * lda + kb + qs * 8, Adst + idx * 16);
        }
#pragma unroll
        for (int u = 0; u < 2; ++u) {
            const int idx = tid + u * 256;
            const int r  = idx >> 2;
            const int qs = (idx & 3) ^ ((idx >> 3) & 3);
            load_lds16(Bb + (size_t)r * ldb + kb + qs * 8, Bdst + idx * 16);
        }
    };

    const int nt = K >> 6;
    // Prologue: tile0 both halves, tile1 k0. 12 loads outstanding.
    stage(0, 0); stage(0, 1); stage(1, 0);

    for (int kt = 0; kt < nt; ++kt) {
        const char* Ablk = smem + (kt & 1) * 2 * HB;
        const char* Bblk = smem + 4 * HB + (kt & 1) * 2 * HB;
        const bool lastT = (kt == nt - 1);

        // ---- phase 1: k-half 0 ----
        if (lastT) WAIT_VM4(); else WAIT_VM8();
        RAW_BARRIER();
        bf16x8 af[4], bfr[4];
#pragma unroll
        for (int im = 0; im < 4; ++im)
            af[im] = *(const bf16x8*)(Ablk + (arow0 + im * 16) * 64 + kqs16);
#pragma unroll
        for (int in = 0; in < 4; ++in)
            bfr[in] = *(const bf16x8*)(Bblk + (brow0 + in * 16) * 64 + kqs16);
        if (kt + 1 < nt) stage(kt + 1, 1);
        RAW_BARRIER();
        PRIO1();
#pragma unroll
        for (int im = 0; im < 4; ++im)
#pragma unroll
            for (int in = 0; in < 4; ++in)
                acc[im][in] = MFMA16(af[im], bfr[in], acc[im][in]);
        PRIO0();

        // ---- phase 2: k-half 1 ----
        if (lastT) WAIT_VM0(); else WAIT_VM8();
        RAW_BARRIER();
#pragma unroll
        for (int im = 0; im < 4; ++im)
            af[im] = *(const bf16x8*)(Ablk + HB + (arow0 + im * 16) * 64 + kqs16);
#pragma unroll
        for (int in = 0; in < 4; ++in)
            bfr[in] = *(const bf16x8*)(Bblk + HB + (brow0 + in * 16) * 64 + kqs16);
        if (kt + 2 < nt) stage(kt + 2, 0);
        RAW_BARRIER();
        PRIO1();
#pragma unroll
        for (int im = 0; im < 4; ++im)
#pragma unroll
            for (int in = 0; in < 4; ++in)
                acc[im][in] = MFMA16(af[im], bfr[in], acc[im][in]);
        PRIO0();
    }

    // Epilogue. C/D frag layout: col = lane&15, row = (lane>>4)*4 + reg
    const size_t dbase = (size_t)z * dStride;
#pragma unroll
    for (int im = 0; im < 4; ++im) {
        const int gmb = m0 + wm * 64 + im * 16 + (laneKq << 2);
        float ri[4];
        if (ROWDIV) {
#pragma unroll
            for (int r = 0; r < 4; ++r)
                ri[r] = 1.f / rowsum[(size_t)z * rsStride + gmb + r];
        }
        float rsum[4] = {0.f, 0.f, 0.f, 0.f};
#pragma unroll
        for (int in = 0; in < 4; ++in) {
            const int gn = n0 + wn * 64 + in * 16 + laneRow;
            float bn = 0.f;
            if (BIAS_MODE == 2) bn = bias[gn];
            if (QKV && n0 >= 1024) {
                union { bf16 h[4]; ushort4 u; } pk;
#pragma unroll
                for (int r = 0; r < 4; ++r)
                    pk.h[r] = __float2bfloat16(acc[im][in][r] + bn);
                *(ushort4*)(vout + (size_t)z * vStride +
                            (size_t)(gn - 1024) * 1024 + gmb) = pk.u;
            } else {
#pragma unroll
                for (int r = 0; r < 4; ++r) {
                    const int gm = gmb + r;
                    float v = acc[im][in][r];
                    if (SCALE_EN) v *= scale;
                    if (EXP_MODE) { v = __expf(v); rsum[r] += v; }
                    if (ROWDIV) v *= ri[r];
                    if (BIAS_MODE == 1) v += bias[gm];
                    if (BIAS_MODE == 2) v += bn;
                    if (RESID_EN)
                        v += resid[(size_t)z * rStride + (size_t)gm * ldr + gn];
                    storeOut(D + dbase + (size_t)gm * ldd + gn, v);
                }
            }
        }
        if (EXP_MODE) {
#pragma unroll
            for (int r = 0; r < 4; ++r) {
                float s = rsum[r];
                s += __shfl_xor(s, 1);
                s += __shfl_xor(s, 2);
                s += __shfl_xor(s, 4);
                s += __shfl_xor(s, 8);
                if (laneRow == 0)
                    atomicAdd(rowsum + (size_t)z * rsStride + gmb + r, s);
            }
        }
    }
}

// ---------------------------------------------------------------------------
// GroupNorm stats: one block per (b, g); 16 ch x 1024 = 16384 contiguous floats
// ---------------------------------------------------------------------------
__global__ __launch_bounds__(256) void gn_stats(const float* __restrict__ x,
                                                float* __restrict__ stats)
{
    const int bg = blockIdx.x;
    const float4* p = (const float4*)(x + (size_t)bg * 16384);
    float s = 0.f, ss = 0.f;
    for (int i = threadIdx.x; i < 4096; i += 256) {
        float4 v = p[i];
        s  += v.x + v.y + v.z + v.w;
        ss += v.x * v.x + v.y * v.y + v.z * v.z + v.w * v.w;
    }
#pragma unroll
    for (int off = 32; off; off >>= 1) {
        s  += __shfl_down(s, off);
        ss += __shfl_down(ss, off);
    }
    __shared__ float rs[4], rss[4];
    const int wv = threadIdx.x >> 6;
    if ((threadIdx.x & 63) == 0) { rs[wv] = s; rss[wv] = ss; }
    __syncthreads();
    if (threadIdx.x == 0) {
        float S  = rs[0] + rs[1] + rs[2] + rs[3];
        float SS = rss[0] + rss[1] + rss[2] + rss[3];
        float mean = S * (1.f / 16384.f);
        float var  = SS * (1.f / 16384.f) - mean * mean;
        stats[2 * bg]     = mean;
        stats[2 * bg + 1] = rsqrtf(var + EPS);
    }
}

// ---------------------------------------------------------------------------
// GN apply + transpose: x (B,512,1024) fp32 -> xnT (B,1024,512) bf16
// ---------------------------------------------------------------------------
__global__ __launch_bounds__(256) void gn_apply_t(const float* __restrict__ x,
                                                  const float* __restrict__ stats,
                                                  const float* __restrict__ gamma,
                                                  const float* __restrict__ beta,
                                                  bf16* __restrict__ xnT)
{
    __shared__ bf16 tile[32][36];
    const int b = blockIdx.z, c0 = blockIdx.y * 32, i0 = blockIdx.x * 32;
    {
        const int cc = threadIdx.x >> 3;
        const int i4 = (threadIdx.x & 7) << 2;
        const int c  = c0 + cc;
        const float mean = stats[2 * ((b << 5) + (c >> 4))];
        const float rstd = stats[2 * ((b << 5) + (c >> 4)) + 1];
        const float a  = gamma[c] * rstd;
        const float bb = beta[c] - mean * a;
        float4 v = *(const float4*)(x + (((size_t)(b * 512 + c)) << 10) + i0 + i4);
        tile[cc][i4 + 0] = __float2bfloat16(v.x * a + bb);
        tile[cc][i4 + 1] = __float2bfloat16(v.y * a + bb);
        tile[cc][i4 + 2] = __float2bfloat16(v.z * a + bb);
        tile[cc][i4 + 3] = __float2bfloat16(v.w * a + bb);
    }
    __syncthreads();
    {
        const int ii = threadIdx.x >> 3;
        const int c4 = (threadIdx.x & 7) << 2;
        union { bf16 h[4]; uint2 u; } pk;
        pk.h[0] = tile[c4 + 0][ii];
        pk.h[1] = tile[c4 + 1][ii];
        pk.h[2] = tile[c4 + 2][ii];
        pk.h[3] = tile[c4 + 3][ii];
        *((uint2*)(xnT + (((size_t)(b * 1024 + i0 + ii)) << 9) + c0 + c4)) = pk.u;
    }
}

// ---------------------------------------------------------------------------
// prep: weights fp32->bf16 (blocks 0..1023), qkv bias concat (block 1024),
// rowsum zero (block 1025).
// ---------------------------------------------------------------------------
__global__ __launch_bounds__(256) void prep(
    const float* __restrict__ wq, const float* __restrict__ wk,
    const float* __restrict__ wv, const float* __restrict__ wp,
    bf16* __restrict__ wqkvb, bf16* __restrict__ wpb,
    const float* __restrict__ bq, const float* __restrict__ bk,
    const float* __restrict__ bv, float* __restrict__ bqkv,
    float* __restrict__ rowsum)
{
    const int id = blockIdx.x;
    if (id < 1024) {
        const int w = id >> 8;
        const float* src = (w == 0) ? wq : (w == 1) ? wk : (w == 2) ? wv : wp;
        bf16* dst = (w < 3) ? (wqkvb + (size_t)w * 262144) : wpb;
        const int g = (id & 255) * 256 + threadIdx.x;
        float4 v = ((const float4*)src)[g];
        union { bf16 h[4]; uint2 u; } pk;
        pk.h[0] = __float2bfloat16(v.x);
        pk.h[1] = __float2bfloat16(v.y);
        pk.h[2] = __float2bfloat16(v.z);
        pk.h[3] = __float2bfloat16(v.w);
        ((uint2*)dst)[g] = pk.u;
    } else if (id == 1024) {
        for (int t = threadIdx.x; t < 1536; t += 256)
            bqkv[t] = (t < 512) ? bq[t] : (t < 1024) ? bk[t - 512] : bv[t - 1024];
    } else {
        float4 zero = {0.f, 0.f, 0.f, 0.f};
#pragma unroll
        for (int j = 0; j < 16; ++j)
            ((float4*)rowsum)[threadIdx.x + j * 256] = zero;
    }
}

// ---------------------------------------------------------------------------
extern "C" void kernel_launch(void* const* d_in, const int* in_sizes, int n_in,
                              void* d_out, int out_size, void* d_ws, size_t ws_size,
                              hipStream_t stream)
{
    const float* x     = (const float*)d_in[0];
    const float* gamma = (const float*)d_in[1];
    const float* beta  = (const float*)d_in[2];
    const float* wq    = (const float*)d_in[3];
    const float* bq    = (const float*)d_in[4];
    const float* wk    = (const float*)d_in[5];
    const float* bk    = (const float*)d_in[6];
    const float* wv    = (const float*)d_in[7];
    const float* bv    = (const float*)d_in[8];
    const float* wp    = (const float*)d_in[9];
    const float* bp    = (const float*)d_in[10];
    float* out = (float*)d_out;

    char* ws = (char*)d_ws;
    size_t off = 0;
    auto alloc = [&](size_t bytes) -> char* {
        char* p = ws + off;
        off += (bytes + 255) & ~(size_t)255;
        return p;
    };

    const long long S  = 1024, C = 512;
    const long long BS = S * C;
    const long long ES = S * S;

    float* stats  = (float*)alloc(512 * 2 * sizeof(float));
    float* bqkv   = (float*)alloc(1536 * sizeof(float));
    float* rowsum = (float*)alloc((size_t)16 * S * sizeof(float));
    bf16* wqkvb = (bf16*)alloc((size_t)3 * C * C * 2);  // [wq; wk; wv]
    bf16* wpb   = (bf16*)alloc((size_t)C * C * 2);
    bf16* xnT   = (bf16*)alloc((size_t)16 * BS * 2);
    bf16* qkT   = (bf16*)alloc((size_t)16 * ES * 2);    // (B,1024,1024): [qT|kT]
    bf16* vv    = (bf16*)alloc((size_t)16 * BS * 2);    // (B,512,1024)
    bf16* O2    = (bf16*)alloc((size_t)16 * BS * 2);

    int CB = 16;
    while (CB > 1 && off + (size_t)CB * ES * 2 + 1024 > ws_size) CB >>= 1;
    bf16* P = (bf16*)alloc((size_t)CB * ES * 2);

    // 64KB dynamic LDS (2 blocks/CU). hipFuncSetAttribute is immediate
    // module state, not a stream op (graph-capture safe).
    hipFuncSetAttribute((const void*)gemm2b<2, 0, 0, 0, 0, 1, bf16>,
                        hipFuncAttributeMaxDynamicSharedMemorySize, 65536);
    hipFuncSetAttribute((const void*)gemm2b<0, 1, 0, 1, 0, 0, bf16>,
                        hipFuncAttributeMaxDynamicSharedMemorySize, 65536);
    hipFuncSetAttribute((const void*)gemm2b<0, 0, 0, 0, 1, 0, bf16>,
                        hipFuncAttributeMaxDynamicSharedMemorySize, 65536);
    hipFuncSetAttribute((const void*)gemm2b<1, 0, 1, 0, 0, 0, float>,
                        hipFuncAttributeMaxDynamicSharedMemorySize, 65536);

    prep<<<1026, 256, 0, stream>>>(wq, wk, wv, wp, wqkvb, wpb, bq, bk, bv,
                                   bqkv, rowsum);

    gn_stats<<<512, 256, 0, stream>>>(x, stats);
    gn_apply_t<<<dim3(32, 16, 16), 256, 0, stream>>>(x, stats, gamma, beta, xnT);

    // QKV proj: M=1024 (i), N=1536 ([q|k|v]), K=512, Z=16. 8x12x16 = 1536 blk.
    gemm2b<2, 0, 0, 0, 0, 1, bf16><<<1536, 256, 65536, stream>>>(
        xnT, BS, 512, wqkvb, 0, 512, qkT, ES, 1024, vv, BS,
        bqkv, nullptr, 0, 0, nullptr, 0, 512, 1.f, /*tpb*/96, /*gx*/12);

    const float scale = 0.044194173824159216f; // 512^-0.5
    for (int b0 = 0; b0 < 16; b0 += CB) {
        // P[i][j] = exp(scale * q_i.k_j); rowsum[i] += (atomics). 8x8 tiles.
        gemm2b<0, 1, 0, 1, 0, 0, bf16><<<CB * 64, 256, 65536, stream>>>(
            qkT + (size_t)b0 * ES, ES, 1024,
            qkT + (size_t)b0 * ES + 512, ES, 1024,
            P, ES, 1024, nullptr, 0,
            nullptr, nullptr, 0, 0, rowsum + (size_t)b0 * S, (int)S,
            512, scale, /*tpb*/64, /*gx*/8);
        // O2[i][c] = (sum_j P[i][j] vv[c][j]) / rowsum[i]. 8x4 tiles, K=1024.
        gemm2b<0, 0, 0, 0, 1, 0, bf16><<<CB * 32, 256, 65536, stream>>>(
            P, ES, 1024,
            vv + (size_t)b0 * BS, BS, 1024,
            O2 + (size_t)b0 * BS, BS, 512, nullptr, 0,
            nullptr, nullptr, 0, 0, rowsum + (size_t)b0 * S, (int)S,
            1024, 1.f, /*tpb*/32, /*gx*/4);
    }

    // out[o][i] = sum_c wp[o][c] O2[i][c] + bp[o] + x[o][i]. 4x8 tiles x16.
    gemm2b<1, 0, 1, 0, 0, 0, float><<<512, 256, 65536, stream>>>(
        wpb, 0, 512, O2, BS, 512, out, BS, 1024, nullptr, 0,
        bp, x, BS, 1024, nullptr, 0, 512, 1.f, /*tpb*/32, /*gx*/8);
}